// Round 3
// baseline (430.713 us; speedup 1.0000x reference)
//
#include <hip/hip_runtime.h>
#include <math.h>

#define D 2048
#define R 128
#define NB 32
#define NS 4096
#define PSTRIDE (D + 16)   // per-chunk partial record: g[D], m, l, pad
#define PQOFF 2048         // float offset: partial qq (8 x 128)
#define COFF 3072          // float offset: scalar c
#define CNTOFF 3076        // int offset: [0]=pro counter, [1..32]=per-b counters
#define PBASE 3200         // float offset: partial records (16B aligned)
#define RSQRT_R 0.08838834764831845f   // 1/sqrt(128)
#define LN_EPS 1e-5f

typedef float f4 __attribute__((ext_vector_type(4)));

// ---- k_pro: qq = Wq^T q + bq (2-stage cross-block reduce w/ spin sync),
//             c = qq.be, w = We.qq.   8 blocks x 256 threads. ----
__global__ __launch_bounds__(256) void k_pro(const float* __restrict__ query,
                                             const float* __restrict__ Wq,
                                             const float* __restrict__ bq,
                                             const float* __restrict__ be,
                                             const float* __restrict__ We,
                                             float* __restrict__ ws,
                                             int* __restrict__ cnt) {
    __shared__ f4 sp[256];
    __shared__ float sqq[R];
    const int tid = threadIdx.x, blk = blockIdx.x;
    const int r4 = tid & 31, dd = tid >> 5;
    const f4* Wq4 = reinterpret_cast<const f4*>(Wq);

    // phase 1: partial qq over this block's 256 d-rows (coalesced f4 reads)
    const int dg0 = blk * 256 + dd * 32;
    f4 acc = (f4)(0.f);
    #pragma unroll
    for (int i = 0; i < 32; ++i)
        acc += query[dg0 + i] * Wq4[(size_t)(dg0 + i) * 32 + r4];
    sp[tid] = acc;
    __syncthreads();
    #pragma unroll
    for (int off = 4; off > 0; off >>= 1) {
        if (dd < off) sp[tid] += sp[tid + off * 32];
        __syncthreads();
    }
    if (tid < 32) reinterpret_cast<f4*>(ws + PQOFF + blk * R)[tid] = sp[tid];
    __threadfence();
    __syncthreads();
    if (tid == 0) {
        atomicAdd(cnt, 1);
        while (__hip_atomic_load(cnt, __ATOMIC_ACQUIRE, __HIP_MEMORY_SCOPE_AGENT) < 8)
            __builtin_amdgcn_s_sleep(2);
    }
    __syncthreads();
    __threadfence();

    // phase 2: full qq (redundant per block), c (block 0 writes)
    if (tid < 32) {
        f4 q = reinterpret_cast<const f4*>(bq)[tid];
        #pragma unroll
        for (int i = 0; i < 8; ++i)
            q += reinterpret_cast<const f4*>(ws + PQOFF + i * R)[tid];
        reinterpret_cast<f4*>(sqq)[tid] = q;
        sp[tid] = q * reinterpret_cast<const f4*>(be)[tid];
    }
    __syncthreads();
    #pragma unroll
    for (int off = 16; off > 0; off >>= 1) {
        if (tid < off) sp[tid] += sp[tid + off];
        __syncthreads();
    }
    if (blk == 0 && tid == 0) {
        const f4 t = sp[0];
        ws[COFF] = t[0] + t[1] + t[2] + t[3];
    }

    // phase 3: w rows for this block's 256 d's
    const int d = blk * 256 + tid;
    const f4* row = reinterpret_cast<const f4*>(We + (size_t)d * R);
    float a0 = 0.f, a1 = 0.f;
    #pragma unroll
    for (int q4 = 0; q4 < 32; q4 += 2) {
        const f4 v0 = row[q4], v1 = row[q4 + 1];
        a0 = fmaf(v0[0], sqq[q4 * 4 + 0], a0);
        a0 = fmaf(v0[1], sqq[q4 * 4 + 1], a0);
        a0 = fmaf(v0[2], sqq[q4 * 4 + 2], a0);
        a0 = fmaf(v0[3], sqq[q4 * 4 + 3], a0);
        a1 = fmaf(v1[0], sqq[q4 * 4 + 4], a1);
        a1 = fmaf(v1[1], sqq[q4 * 4 + 5], a1);
        a1 = fmaf(v1[2], sqq[q4 * 4 + 6], a1);
        a1 = fmaf(v1[3], sqq[q4 * 4 + 7], a1);
    }
    ws[d] = a0 + a1;
}

// ---- k_main: streaming pass + fused cross-chunk merge (last block per b). ----
__global__ __launch_bounds__(256) void k_main(const float* __restrict__ X,
                                              const float* __restrict__ ws,
                                              float* __restrict__ partials,
                                              int* __restrict__ cntb,
                                              const float* __restrict__ gamma,
                                              const float* __restrict__ beta,
                                              float* __restrict__ out,
                                              int cpb, int rpc) {
    const int b = blockIdx.y, chunk = blockIdx.x;
    const int tid = threadIdx.x;
    const int lane = tid & 63, wid = tid >> 6;

    f4 w4[8];
    #pragma unroll
    for (int k = 0; k < 8; ++k)
        w4[k] = *reinterpret_cast<const f4*>(ws + lane * 4 + k * 256);
    const float c = ws[COFF];

    const int s0 = chunk * rpc;
    const int s1 = s0 + rpc;

    float m = -INFINITY, l = 0.f;
    f4 acc[8];
    #pragma unroll
    for (int k = 0; k < 8; ++k) acc[k] = (f4)(0.f);

    for (int s = s0 + wid; s < s1; s += 8) {
        const float* ra = X + ((size_t)b * NS + s) * D + lane * 4;
        const float* rb = ra + 4 * D;
        f4 xa[8], xb[8];
        #pragma unroll
        for (int k = 0; k < 8; ++k)
            xa[k] = __builtin_nontemporal_load(reinterpret_cast<const f4*>(ra + k * 256));
        #pragma unroll
        for (int k = 0; k < 8; ++k)
            xb[k] = __builtin_nontemporal_load(reinterpret_cast<const f4*>(rb + k * 256));

        float da0 = 0.f, da1 = 0.f, db0 = 0.f, db1 = 0.f;
        #pragma unroll
        for (int k = 0; k < 8; k += 2) {
            da0 = fmaf(xa[k][0], w4[k][0], da0);
            da0 = fmaf(xa[k][1], w4[k][1], da0);
            da0 = fmaf(xa[k][2], w4[k][2], da0);
            da0 = fmaf(xa[k][3], w4[k][3], da0);
            da1 = fmaf(xa[k+1][0], w4[k+1][0], da1);
            da1 = fmaf(xa[k+1][1], w4[k+1][1], da1);
            da1 = fmaf(xa[k+1][2], w4[k+1][2], da1);
            da1 = fmaf(xa[k+1][3], w4[k+1][3], da1);
            db0 = fmaf(xb[k][0], w4[k][0], db0);
            db0 = fmaf(xb[k][1], w4[k][1], db0);
            db0 = fmaf(xb[k][2], w4[k][2], db0);
            db0 = fmaf(xb[k][3], w4[k][3], db0);
            db1 = fmaf(xb[k+1][0], w4[k+1][0], db1);
            db1 = fmaf(xb[k+1][1], w4[k+1][1], db1);
            db1 = fmaf(xb[k+1][2], w4[k+1][2], db1);
            db1 = fmaf(xb[k+1][3], w4[k+1][3], db1);
        }
        float da = da0 + da1, db = db0 + db1;
        #pragma unroll
        for (int off = 32; off > 0; off >>= 1) {
            da += __shfl_xor(da, off, 64);
            db += __shfl_xor(db, off, 64);
        }
        const float sa = (da + c) * RSQRT_R;
        const float sb = (db + c) * RSQRT_R;
        const float mn = fmaxf(sa, sb);

        if (mn > m) {                 // wave-uniform
            const float f = __expf(m - mn);
            l *= f;
            #pragma unroll
            for (int k = 0; k < 8; ++k) acc[k] *= f;
            m = mn;
        }
        const float pa = __expf(sa - m);
        const float pb = __expf(sb - m);
        l += pa + pb;
        #pragma unroll
        for (int k = 0; k < 8; ++k) acc[k] += pa * xa[k] + pb * xb[k];
    }

    // ---- combine 4 waves, write partial record ----
    __shared__ float sm[4], sl[4];
    __shared__ __align__(16) float sacc[4][D];
    if (lane == 0) { sm[wid] = m; sl[wid] = l; }
    __syncthreads();
    const float mb = fmaxf(fmaxf(sm[0], sm[1]), fmaxf(sm[2], sm[3]));
    const float lb = __expf(sm[0] - mb) * sl[0] + __expf(sm[1] - mb) * sl[1] +
                     __expf(sm[2] - mb) * sl[2] + __expf(sm[3] - mb) * sl[3];
    const float coeff = __expf(m - mb);
    #pragma unroll
    for (int k = 0; k < 8; ++k)
        *reinterpret_cast<f4*>(&sacc[wid][lane * 4 + k * 256]) = acc[k] * coeff;
    __syncthreads();

    float* rec = partials + (size_t)(b * cpb + chunk) * PSTRIDE;
    {
        const int i0 = tid * 4, i1 = 1024 + tid * 4;
        f4 r0 = *reinterpret_cast<const f4*>(&sacc[0][i0]) +
                *reinterpret_cast<const f4*>(&sacc[1][i0]) +
                *reinterpret_cast<const f4*>(&sacc[2][i0]) +
                *reinterpret_cast<const f4*>(&sacc[3][i0]);
        f4 r1 = *reinterpret_cast<const f4*>(&sacc[0][i1]) +
                *reinterpret_cast<const f4*>(&sacc[1][i1]) +
                *reinterpret_cast<const f4*>(&sacc[2][i1]) +
                *reinterpret_cast<const f4*>(&sacc[3][i1]);
        *reinterpret_cast<f4*>(rec + i0) = r0;
        *reinterpret_cast<f4*>(rec + i1) = r1;
    }
    if (tid == 0) { rec[D] = mb; rec[D + 1] = lb; }

    // ---- last block for this b merges all chunks + LayerNorm + output ----
    __threadfence();
    __syncthreads();
    __shared__ int slast;
    if (tid == 0) {
        const int old = atomicAdd(cntb + b, 1);
        slast = (old == cpb - 1);
    }
    __syncthreads();
    if (!slast) return;
    __threadfence();   // acquire: see other blocks' records

    const float* pbase = partials + (size_t)b * cpb * PSTRIDE;
    __shared__ float smm[32], sll[32];
    if (tid < cpb) {
        smm[tid] = pbase[(size_t)tid * PSTRIDE + D];
        sll[tid] = pbase[(size_t)tid * PSTRIDE + D + 1];
    }
    __syncthreads();
    float mg = -INFINITY;
    for (int i = 0; i < cpb; ++i) mg = fmaxf(mg, smm[i]);
    float lg = 0.f;
    for (int i = 0; i < cpb; ++i) lg += __expf(smm[i] - mg) * sll[i];
    const float inv_l = 1.f / lg;

    f4 g0 = (f4)(0.f), g1 = (f4)(0.f);
    for (int i = 0; i < cpb; ++i) {
        const float cf = __expf(smm[i] - mg);
        const f4 a0 = *reinterpret_cast<const f4*>(pbase + (size_t)i * PSTRIDE + tid * 4);
        const f4 a1 = *reinterpret_cast<const f4*>(pbase + (size_t)i * PSTRIDE + 1024 + tid * 4);
        g0 += cf * a0;
        g1 += cf * a1;
    }
    g0 *= inv_l; g1 *= inv_l;

    const float s1v = g0[0]+g0[1]+g0[2]+g0[3]+g1[0]+g1[1]+g1[2]+g1[3];
    const float s2v = g0[0]*g0[0]+g0[1]*g0[1]+g0[2]*g0[2]+g0[3]*g0[3]+
                      g1[0]*g1[0]+g1[1]*g1[1]+g1[2]*g1[2]+g1[3]*g1[3];
    __shared__ float sA[256], sB[256];
    sA[tid] = s1v; sB[tid] = s2v;
    __syncthreads();
    for (int off = 128; off > 0; off >>= 1) {
        if (tid < off) { sA[tid] += sA[tid + off]; sB[tid] += sB[tid + off]; }
        __syncthreads();
    }
    const float mean = sA[0] / (float)D;
    const float var  = sB[0] / (float)D - mean * mean;
    const float rstd = rsqrtf(var + LN_EPS);

    const f4 ga0 = *reinterpret_cast<const f4*>(gamma + tid * 4);
    const f4 ga1 = *reinterpret_cast<const f4*>(gamma + 1024 + tid * 4);
    const f4 be0 = *reinterpret_cast<const f4*>(beta + tid * 4);
    const f4 be1 = *reinterpret_cast<const f4*>(beta + 1024 + tid * 4);
    f4 o0, o1;
    o0[0] = (g0[0] - mean) * rstd * ga0[0] + be0[0];
    o0[1] = (g0[1] - mean) * rstd * ga0[1] + be0[1];
    o0[2] = (g0[2] - mean) * rstd * ga0[2] + be0[2];
    o0[3] = (g0[3] - mean) * rstd * ga0[3] + be0[3];
    o1[0] = (g1[0] - mean) * rstd * ga1[0] + be1[0];
    o1[1] = (g1[1] - mean) * rstd * ga1[1] + be1[1];
    o1[2] = (g1[2] - mean) * rstd * ga1[2] + be1[2];
    o1[3] = (g1[3] - mean) * rstd * ga1[3] + be1[3];
    *reinterpret_cast<f4*>(out + (size_t)b * D + tid * 4) = o0;
    *reinterpret_cast<f4*>(out + (size_t)b * D + 1024 + tid * 4) = o1;
}

extern "C" void kernel_launch(void* const* d_in, const int* in_sizes, int n_in,
                              void* d_out, int out_size, void* d_ws, size_t ws_size,
                              hipStream_t stream) {
    const float* X     = (const float*)d_in[0];
    const float* query = (const float*)d_in[1];
    const float* Wq    = (const float*)d_in[2];
    const float* bq    = (const float*)d_in[3];
    const float* We    = (const float*)d_in[4];
    const float* be    = (const float*)d_in[5];
    const float* gamma = (const float*)d_in[6];
    const float* beta  = (const float*)d_in[7];
    float* out = (float*)d_out;
    float* ws  = (float*)d_ws;
    int*   cnt = (int*)((char*)d_ws + (size_t)CNTOFF * 4);

    size_t avail = ws_size / 4;
    int cpb = 32;
    while (cpb > 1 && (size_t)PBASE + (size_t)NB * cpb * PSTRIDE > avail) cpb >>= 1;
    const int rpc = NS / cpb;

    hipMemsetAsync((void*)cnt, 0, 33 * sizeof(int), stream);
    hipLaunchKernelGGL(k_pro, dim3(8), dim3(256), 0, stream,
                       query, Wq, bq, be, We, ws, cnt);
    hipLaunchKernelGGL(k_main, dim3(cpb, NB), dim3(256), 0, stream,
                       X, ws, ws + PBASE, cnt + 1, gamma, beta, out, cpb, rpc);
}

// Round 4
// 182.869 us; speedup vs baseline: 2.3553x; 2.3553x over previous
//
#include <hip/hip_runtime.h>
#include <math.h>

#define D 2048
#define R 128
#define NB 32
#define NS 4096
#define PSTRIDE (D + 16)   // per-chunk partial record: g[D], m, l, pad (16B-aligned stride)
#define PQ 2304            // float offset of partialQ (32 x 128) in ws
#define PBASE 6656         // float offset of partial records in ws (16B aligned)
#define RSQRT_R 0.08838834764831845f   // 1/sqrt(128)
#define LN_EPS 1e-5f

typedef float f4 __attribute__((ext_vector_type(4)));

// ---- k_qq1: partialQ[blk][r] = sum_{d in blk's 64 rows} query[d]*Wq[d,r].
//      32 blocks x 256 thr; thread (r4=tid&31, dl=tid>>5) does 8 independent f4 loads. ----
__global__ __launch_bounds__(256) void k_qq1(const float* __restrict__ query,
                                             const float* __restrict__ Wq,
                                             float* __restrict__ pq) {
    __shared__ f4 sp[256];
    const int tid = threadIdx.x, blk = blockIdx.x;
    const int r4 = tid & 31, dl = tid >> 5;
    const f4* Wq4 = reinterpret_cast<const f4*>(Wq);
    const int d0 = blk * 64 + dl * 8;
    f4 acc = (f4)(0.f);
    #pragma unroll
    for (int i = 0; i < 8; ++i)
        acc += query[d0 + i] * Wq4[(size_t)(d0 + i) * 32 + r4];
    sp[tid] = acc;
    __syncthreads();
    #pragma unroll
    for (int off = 4; off > 0; off >>= 1) {
        if (dl < off) sp[tid] += sp[tid + off * 32];
        __syncthreads();
    }
    if (tid < 32) reinterpret_cast<f4*>(pq + blk * R)[tid] = sp[tid];
}

// ---- k_w: qq = bq + sum_i partialQ[i]; c = qq.be; w[d] = sum_r We[d,r]*qq[r].
//      8 blocks x 256 thr. ----
__global__ __launch_bounds__(256) void k_w(const float* __restrict__ We,
                                           const float* __restrict__ bq,
                                           const float* __restrict__ be,
                                           float* __restrict__ ws) {
    __shared__ float sqq[R];
    __shared__ f4 sc[32];
    const int tid = threadIdx.x;
    const float* pq = ws + PQ;
    if (tid < 32) {
        f4 q = reinterpret_cast<const f4*>(bq)[tid];
        #pragma unroll
        for (int i = 0; i < 32; ++i)
            q += reinterpret_cast<const f4*>(pq + i * R)[tid];
        reinterpret_cast<f4*>(sqq)[tid] = q;
        sc[tid] = q * reinterpret_cast<const f4*>(be)[tid];
    }
    __syncthreads();
    if (blockIdx.x == 0 && tid == 0) {
        f4 t = (f4)(0.f);
        #pragma unroll
        for (int i = 0; i < 32; ++i) t += sc[i];
        ws[D + R] = t[0] + t[1] + t[2] + t[3];
    }

    const int d = blockIdx.x * 256 + tid;
    const f4* row = reinterpret_cast<const f4*>(We + (size_t)d * R);
    float a0 = 0.f, a1 = 0.f;
    #pragma unroll
    for (int r4 = 0; r4 < R / 4; r4 += 2) {
        const f4 v0 = row[r4], v1 = row[r4 + 1];
        a0 = fmaf(v0[0], sqq[r4 * 4 + 0], a0);
        a0 = fmaf(v0[1], sqq[r4 * 4 + 1], a0);
        a0 = fmaf(v0[2], sqq[r4 * 4 + 2], a0);
        a0 = fmaf(v0[3], sqq[r4 * 4 + 3], a0);
        a1 = fmaf(v1[0], sqq[r4 * 4 + 4], a1);
        a1 = fmaf(v1[1], sqq[r4 * 4 + 5], a1);
        a1 = fmaf(v1[2], sqq[r4 * 4 + 6], a1);
        a1 = fmaf(v1[3], sqq[r4 * 4 + 7], a1);
    }
    ws[d] = a0 + a1;
}

// ---- k_main: streaming pass. One block = (b, s-chunk). 4 waves, wave owns rows
// s0+wid, +4, ... ; 2-row unroll; online softmax; parallel LDS combine. ----
__global__ __launch_bounds__(256) void k_main(const float* __restrict__ X,
                                              const float* __restrict__ ws,
                                              float* __restrict__ partials,
                                              int cpb, int rpc) {
    const int b = blockIdx.y, chunk = blockIdx.x;
    const int tid = threadIdx.x;
    const int lane = tid & 63, wid = tid >> 6;

    f4 w4[8];
    #pragma unroll
    for (int k = 0; k < 8; ++k)
        w4[k] = *reinterpret_cast<const f4*>(ws + lane * 4 + k * 256);
    const float c = ws[D + R];

    const int s0 = chunk * rpc;
    const int s1 = s0 + rpc;

    float m = -INFINITY, l = 0.f;
    f4 acc[8];
    #pragma unroll
    for (int k = 0; k < 8; ++k) acc[k] = (f4)(0.f);

    for (int s = s0 + wid; s < s1; s += 8) {
        const float* ra = X + ((size_t)b * NS + s) * D + lane * 4;
        const float* rb = ra + 4 * D;
        f4 xa[8], xb[8];
        #pragma unroll
        for (int k = 0; k < 8; ++k)
            xa[k] = __builtin_nontemporal_load(reinterpret_cast<const f4*>(ra + k * 256));
        #pragma unroll
        for (int k = 0; k < 8; ++k)
            xb[k] = __builtin_nontemporal_load(reinterpret_cast<const f4*>(rb + k * 256));

        float da0 = 0.f, da1 = 0.f, db0 = 0.f, db1 = 0.f;
        #pragma unroll
        for (int k = 0; k < 8; k += 2) {
            da0 = fmaf(xa[k][0], w4[k][0], da0);
            da0 = fmaf(xa[k][1], w4[k][1], da0);
            da0 = fmaf(xa[k][2], w4[k][2], da0);
            da0 = fmaf(xa[k][3], w4[k][3], da0);
            da1 = fmaf(xa[k+1][0], w4[k+1][0], da1);
            da1 = fmaf(xa[k+1][1], w4[k+1][1], da1);
            da1 = fmaf(xa[k+1][2], w4[k+1][2], da1);
            da1 = fmaf(xa[k+1][3], w4[k+1][3], da1);
            db0 = fmaf(xb[k][0], w4[k][0], db0);
            db0 = fmaf(xb[k][1], w4[k][1], db0);
            db0 = fmaf(xb[k][2], w4[k][2], db0);
            db0 = fmaf(xb[k][3], w4[k][3], db0);
            db1 = fmaf(xb[k+1][0], w4[k+1][0], db1);
            db1 = fmaf(xb[k+1][1], w4[k+1][1], db1);
            db1 = fmaf(xb[k+1][2], w4[k+1][2], db1);
            db1 = fmaf(xb[k+1][3], w4[k+1][3], db1);
        }
        float da = da0 + da1, db = db0 + db1;
        #pragma unroll
        for (int off = 32; off > 0; off >>= 1) {
            da += __shfl_xor(da, off, 64);
            db += __shfl_xor(db, off, 64);
        }
        const float sa = (da + c) * RSQRT_R;
        const float sb = (db + c) * RSQRT_R;
        const float mn = fmaxf(sa, sb);

        if (mn > m) {                 // wave-uniform
            const float f = __expf(m - mn);
            l *= f;
            #pragma unroll
            for (int k = 0; k < 8; ++k) acc[k] *= f;
            m = mn;
        }
        const float pa = __expf(sa - m);
        const float pb = __expf(sb - m);
        l += pa + pb;
        #pragma unroll
        for (int k = 0; k < 8; ++k) acc[k] += pa * xa[k] + pb * xb[k];
    }

    // ---- parallel combine of the 4 waves ----
    __shared__ float sm[4], sl[4];
    __shared__ __align__(16) float sacc[4][D];
    if (lane == 0) { sm[wid] = m; sl[wid] = l; }
    __syncthreads();
    const float mb = fmaxf(fmaxf(sm[0], sm[1]), fmaxf(sm[2], sm[3]));
    const float lb = __expf(sm[0] - mb) * sl[0] + __expf(sm[1] - mb) * sl[1] +
                     __expf(sm[2] - mb) * sl[2] + __expf(sm[3] - mb) * sl[3];
    const float coeff = __expf(m - mb);
    #pragma unroll
    for (int k = 0; k < 8; ++k)
        *reinterpret_cast<f4*>(&sacc[wid][lane * 4 + k * 256]) = acc[k] * coeff;
    __syncthreads();

    float* rec = partials + (size_t)(b * cpb + chunk) * PSTRIDE;
    {
        const int i0 = tid * 4, i1 = 1024 + tid * 4;
        f4 r0 = *reinterpret_cast<const f4*>(&sacc[0][i0]) +
                *reinterpret_cast<const f4*>(&sacc[1][i0]) +
                *reinterpret_cast<const f4*>(&sacc[2][i0]) +
                *reinterpret_cast<const f4*>(&sacc[3][i0]);
        f4 r1 = *reinterpret_cast<const f4*>(&sacc[0][i1]) +
                *reinterpret_cast<const f4*>(&sacc[1][i1]) +
                *reinterpret_cast<const f4*>(&sacc[2][i1]) +
                *reinterpret_cast<const f4*>(&sacc[3][i1]);
        *reinterpret_cast<f4*>(rec + i0) = r0;
        *reinterpret_cast<f4*>(rec + i1) = r1;
    }
    if (tid == 0) { rec[D] = mb; rec[D + 1] = lb; }
}

// ---- k_fin: cross-chunk softmax merge + normalize + LayerNorm. One block per b. ----
__global__ __launch_bounds__(512) void k_fin(const float* __restrict__ partials,
                                             const float* __restrict__ gamma,
                                             const float* __restrict__ beta,
                                             float* __restrict__ out, int cpb) {
    const int b = blockIdx.x, tid = threadIdx.x;
    __shared__ float scoef[64];
    __shared__ float sredA[512], sredB[512];
    const float* pb = partials + (size_t)b * cpb * PSTRIDE;

    float mloc = -INFINITY;
    for (int i = tid; i < cpb; i += 512) mloc = fmaxf(mloc, pb[i * PSTRIDE + D]);
    sredA[tid] = mloc; __syncthreads();
    for (int off = 256; off > 0; off >>= 1) {
        if (tid < off) sredA[tid] = fmaxf(sredA[tid], sredA[tid + off]);
        __syncthreads();
    }
    const float mg = sredA[0];
    __syncthreads();

    float lloc = 0.f;
    for (int i = tid; i < cpb; i += 512) {
        const float cf = __expf(pb[i * PSTRIDE + D] - mg);
        scoef[i] = cf;
        lloc += cf * pb[i * PSTRIDE + D + 1];
    }
    sredA[tid] = lloc; __syncthreads();
    for (int off = 256; off > 0; off >>= 1) {
        if (tid < off) sredA[tid] += sredA[tid + off];
        __syncthreads();
    }
    const float inv_l = 1.f / sredA[0];
    __syncthreads();

    f4 g = (f4)(0.f);
    for (int i = 0; i < cpb; ++i) {
        const float cf = scoef[i];
        const f4 a = *reinterpret_cast<const f4*>(pb + (size_t)i * PSTRIDE + tid * 4);
        g[0] = fmaf(cf, a[0], g[0]);
        g[1] = fmaf(cf, a[1], g[1]);
        g[2] = fmaf(cf, a[2], g[2]);
        g[3] = fmaf(cf, a[3], g[3]);
    }
    g *= inv_l;

    const float s1 = g[0] + g[1] + g[2] + g[3];
    const float s2 = g[0]*g[0] + g[1]*g[1] + g[2]*g[2] + g[3]*g[3];
    sredA[tid] = s1; sredB[tid] = s2; __syncthreads();
    for (int off = 256; off > 0; off >>= 1) {
        if (tid < off) { sredA[tid] += sredA[tid + off]; sredB[tid] += sredB[tid + off]; }
        __syncthreads();
    }
    const float mean = sredA[0] / (float)D;
    const float var = sredB[0] / (float)D - mean * mean;
    const float rstd = rsqrtf(var + LN_EPS);

    const f4 ga = *reinterpret_cast<const f4*>(gamma + tid * 4);
    const f4 be = *reinterpret_cast<const f4*>(beta + tid * 4);
    f4 o;
    o[0] = (g[0] - mean) * rstd * ga[0] + be[0];
    o[1] = (g[1] - mean) * rstd * ga[1] + be[1];
    o[2] = (g[2] - mean) * rstd * ga[2] + be[2];
    o[3] = (g[3] - mean) * rstd * ga[3] + be[3];
    *reinterpret_cast<f4*>(out + (size_t)b * D + tid * 4) = o;
}

extern "C" void kernel_launch(void* const* d_in, const int* in_sizes, int n_in,
                              void* d_out, int out_size, void* d_ws, size_t ws_size,
                              hipStream_t stream) {
    const float* X     = (const float*)d_in[0];
    const float* query = (const float*)d_in[1];
    const float* Wq    = (const float*)d_in[2];
    const float* bq    = (const float*)d_in[3];
    const float* We    = (const float*)d_in[4];
    const float* be    = (const float*)d_in[5];
    const float* gamma = (const float*)d_in[6];
    const float* beta  = (const float*)d_in[7];
    float* out = (float*)d_out;
    float* ws  = (float*)d_ws;

    size_t avail = ws_size / 4;
    int cpb = 32;
    while (cpb > 1 && (size_t)PBASE + (size_t)NB * cpb * PSTRIDE > avail) cpb >>= 1;
    const int rpc = NS / cpb;

    hipLaunchKernelGGL(k_qq1, dim3(32), dim3(256), 0, stream, query, Wq, ws + PQ);
    hipLaunchKernelGGL(k_w, dim3(D / 256), dim3(256), 0, stream, We, bq, be, ws);
    hipLaunchKernelGGL(k_main, dim3(cpb, NB), dim3(256), 0, stream,
                       X, ws, ws + PBASE, cpb, rpc);
    hipLaunchKernelGGL(k_fin, dim3(NB), dim3(512), 0, stream,
                       ws + PBASE, gamma, beta, out, cpb);
}

// Round 5
// 181.228 us; speedup vs baseline: 2.3766x; 1.0091x over previous
//
#include <hip/hip_runtime.h>
#include <math.h>

#define D 2048
#define R 128
#define NB 32
#define NS 4096
#define PSTRIDE (D + 16)   // per-chunk partial record: g[D], m, l, pad (16B-aligned stride)
#define PQ 2304            // float offset of partialQ (32 x 128) in ws
#define PBASE 6656         // float offset of partial records in ws (16B aligned)
#define RSQRT_R 0.08838834764831845f   // 1/sqrt(128)
#define LN_EPS 1e-5f

typedef float f4 __attribute__((ext_vector_type(4)));

// ---- k_qq1: partialQ[blk][r] = sum_{d in blk's 64 rows} query[d]*Wq[d,r].
//      32 blocks x 256 thr. ----
__global__ __launch_bounds__(256) void k_qq1(const float* __restrict__ query,
                                             const float* __restrict__ Wq,
                                             float* __restrict__ pq) {
    __shared__ f4 sp[256];
    const int tid = threadIdx.x, blk = blockIdx.x;
    const int r4 = tid & 31, dl = tid >> 5;
    const f4* Wq4 = reinterpret_cast<const f4*>(Wq);
    const int d0 = blk * 64 + dl * 8;
    f4 acc = (f4)(0.f);
    #pragma unroll
    for (int i = 0; i < 8; ++i)
        acc += query[d0 + i] * Wq4[(size_t)(d0 + i) * 32 + r4];
    sp[tid] = acc;
    __syncthreads();
    #pragma unroll
    for (int off = 4; off > 0; off >>= 1) {
        if (dl < off) sp[tid] += sp[tid + off * 32];
        __syncthreads();
    }
    if (tid < 32) reinterpret_cast<f4*>(pq + blk * R)[tid] = sp[tid];
}

// ---- k_w: qq = bq + sum_i partialQ[i] (redundant per thread); c = qq.be (blk0);
//      w[d] = sum_r We[d,r]*qq[r].  32 blocks x 256 thr, 64 We-rows per block.
//      Thread (r4=tid&31, dl=tid>>5) covers rows d0+dl*8..+7, column slice r4. ----
__global__ __launch_bounds__(256) void k_w(const float* __restrict__ We,
                                           const float* __restrict__ bq,
                                           const float* __restrict__ be,
                                           float* __restrict__ ws) {
    const int tid = threadIdx.x, blk = blockIdx.x;
    const int r4 = tid & 31, dl = tid >> 5;
    const float* pq = ws + PQ;

    // combine partialQ -> this thread's qq fragment (f4 at column r4)
    f4 q = reinterpret_cast<const f4*>(bq)[r4];
    #pragma unroll
    for (int i = 0; i < 32; ++i)
        q += reinterpret_cast<const f4*>(pq + i * R)[r4];

    // c = qq . be  (block 0, first 32 lanes; shfl-reduce within the 32-group)
    if (blk == 0 && dl == 0) {
        const f4 bev = reinterpret_cast<const f4*>(be)[r4];
        float cp = q[0]*bev[0] + q[1]*bev[1] + q[2]*bev[2] + q[3]*bev[3];
        #pragma unroll
        for (int off = 16; off > 0; off >>= 1) cp += __shfl_xor(cp, off, 64);
        if (r4 == 0) ws[D + R] = cp;
    }

    // 8 rows x f4 partial dot, coalesced: lanes 0..31 cover a row's 512 B
    const int d0 = blk * 64 + dl * 8;
    const f4* We4 = reinterpret_cast<const f4*>(We);
    float p[8];
    #pragma unroll
    for (int i = 0; i < 8; ++i) {
        const f4 v = We4[(size_t)(d0 + i) * 32 + r4];
        p[i] = v[0]*q[0] + v[1]*q[1] + v[2]*q[2] + v[3]*q[3];
    }
    #pragma unroll
    for (int i = 0; i < 8; ++i) {
        #pragma unroll
        for (int off = 16; off > 0; off >>= 1) p[i] += __shfl_xor(p[i], off, 64);
    }
    if (r4 == 0) {
        #pragma unroll
        for (int i = 0; i < 8; ++i) ws[d0 + i] = p[i];
    }
}

// ---- k_main: streaming pass. One block = (b, s-chunk). 4 waves, wave owns rows
// s0+wid, +4, ... ; 2-row unroll; online softmax; parallel LDS combine. ----
__global__ __launch_bounds__(256) void k_main(const float* __restrict__ X,
                                              const float* __restrict__ ws,
                                              float* __restrict__ partials,
                                              int cpb, int rpc) {
    const int b = blockIdx.y, chunk = blockIdx.x;
    const int tid = threadIdx.x;
    const int lane = tid & 63, wid = tid >> 6;

    f4 w4[8];
    #pragma unroll
    for (int k = 0; k < 8; ++k)
        w4[k] = *reinterpret_cast<const f4*>(ws + lane * 4 + k * 256);
    const float c = ws[D + R];

    const int s0 = chunk * rpc;
    const int s1 = s0 + rpc;

    float m = -INFINITY, l = 0.f;
    f4 acc[8];
    #pragma unroll
    for (int k = 0; k < 8; ++k) acc[k] = (f4)(0.f);

    for (int s = s0 + wid; s < s1; s += 8) {
        const float* ra = X + ((size_t)b * NS + s) * D + lane * 4;
        const float* rb = ra + 4 * D;
        f4 xa[8], xb[8];
        #pragma unroll
        for (int k = 0; k < 8; ++k)
            xa[k] = __builtin_nontemporal_load(reinterpret_cast<const f4*>(ra + k * 256));
        #pragma unroll
        for (int k = 0; k < 8; ++k)
            xb[k] = __builtin_nontemporal_load(reinterpret_cast<const f4*>(rb + k * 256));

        float da0 = 0.f, da1 = 0.f, db0 = 0.f, db1 = 0.f;
        #pragma unroll
        for (int k = 0; k < 8; k += 2) {
            da0 = fmaf(xa[k][0], w4[k][0], da0);
            da0 = fmaf(xa[k][1], w4[k][1], da0);
            da0 = fmaf(xa[k][2], w4[k][2], da0);
            da0 = fmaf(xa[k][3], w4[k][3], da0);
            da1 = fmaf(xa[k+1][0], w4[k+1][0], da1);
            da1 = fmaf(xa[k+1][1], w4[k+1][1], da1);
            da1 = fmaf(xa[k+1][2], w4[k+1][2], da1);
            da1 = fmaf(xa[k+1][3], w4[k+1][3], da1);
            db0 = fmaf(xb[k][0], w4[k][0], db0);
            db0 = fmaf(xb[k][1], w4[k][1], db0);
            db0 = fmaf(xb[k][2], w4[k][2], db0);
            db0 = fmaf(xb[k][3], w4[k][3], db0);
            db1 = fmaf(xb[k+1][0], w4[k+1][0], db1);
            db1 = fmaf(xb[k+1][1], w4[k+1][1], db1);
            db1 = fmaf(xb[k+1][2], w4[k+1][2], db1);
            db1 = fmaf(xb[k+1][3], w4[k+1][3], db1);
        }
        float da = da0 + da1, db = db0 + db1;
        #pragma unroll
        for (int off = 32; off > 0; off >>= 1) {
            da += __shfl_xor(da, off, 64);
            db += __shfl_xor(db, off, 64);
        }
        const float sa = (da + c) * RSQRT_R;
        const float sb = (db + c) * RSQRT_R;
        const float mn = fmaxf(sa, sb);

        if (mn > m) {                 // wave-uniform
            const float f = __expf(m - mn);
            l *= f;
            #pragma unroll
            for (int k = 0; k < 8; ++k) acc[k] *= f;
            m = mn;
        }
        const float pa = __expf(sa - m);
        const float pb = __expf(sb - m);
        l += pa + pb;
        #pragma unroll
        for (int k = 0; k < 8; ++k) acc[k] += pa * xa[k] + pb * xb[k];
    }

    // ---- parallel combine of the 4 waves ----
    __shared__ float sm[4], sl[4];
    __shared__ __align__(16) float sacc[4][D];
    if (lane == 0) { sm[wid] = m; sl[wid] = l; }
    __syncthreads();
    const float mb = fmaxf(fmaxf(sm[0], sm[1]), fmaxf(sm[2], sm[3]));
    const float lb = __expf(sm[0] - mb) * sl[0] + __expf(sm[1] - mb) * sl[1] +
                     __expf(sm[2] - mb) * sl[2] + __expf(sm[3] - mb) * sl[3];
    const float coeff = __expf(m - mb);
    #pragma unroll
    for (int k = 0; k < 8; ++k)
        *reinterpret_cast<f4*>(&sacc[wid][lane * 4 + k * 256]) = acc[k] * coeff;
    __syncthreads();

    float* rec = partials + (size_t)(b * cpb + chunk) * PSTRIDE;
    {
        const int i0 = tid * 4, i1 = 1024 + tid * 4;
        f4 r0 = *reinterpret_cast<const f4*>(&sacc[0][i0]) +
                *reinterpret_cast<const f4*>(&sacc[1][i0]) +
                *reinterpret_cast<const f4*>(&sacc[2][i0]) +
                *reinterpret_cast<const f4*>(&sacc[3][i0]);
        f4 r1 = *reinterpret_cast<const f4*>(&sacc[0][i1]) +
                *reinterpret_cast<const f4*>(&sacc[1][i1]) +
                *reinterpret_cast<const f4*>(&sacc[2][i1]) +
                *reinterpret_cast<const f4*>(&sacc[3][i1]);
        *reinterpret_cast<f4*>(rec + i0) = r0;
        *reinterpret_cast<f4*>(rec + i1) = r1;
    }
    if (tid == 0) { rec[D] = mb; rec[D + 1] = lb; }
}

// ---- k_fin: cross-chunk softmax merge + normalize + LayerNorm. One block per b. ----
__global__ __launch_bounds__(512) void k_fin(const float* __restrict__ partials,
                                             const float* __restrict__ gamma,
                                             const float* __restrict__ beta,
                                             float* __restrict__ out, int cpb) {
    const int b = blockIdx.x, tid = threadIdx.x;
    __shared__ float scoef[64];
    __shared__ float sredA[512], sredB[512];
    const float* pb = partials + (size_t)b * cpb * PSTRIDE;

    float mloc = -INFINITY;
    for (int i = tid; i < cpb; i += 512) mloc = fmaxf(mloc, pb[i * PSTRIDE + D]);
    sredA[tid] = mloc; __syncthreads();
    for (int off = 256; off > 0; off >>= 1) {
        if (tid < off) sredA[tid] = fmaxf(sredA[tid], sredA[tid + off]);
        __syncthreads();
    }
    const float mg = sredA[0];
    __syncthreads();

    float lloc = 0.f;
    for (int i = tid; i < cpb; i += 512) {
        const float cf = __expf(pb[i * PSTRIDE + D] - mg);
        scoef[i] = cf;
        lloc += cf * pb[i * PSTRIDE + D + 1];
    }
    sredA[tid] = lloc; __syncthreads();
    for (int off = 256; off > 0; off >>= 1) {
        if (tid < off) sredA[tid] += sredA[tid + off];
        __syncthreads();
    }
    const float inv_l = 1.f / sredA[0];
    __syncthreads();

    f4 g = (f4)(0.f);
    for (int i = 0; i < cpb; ++i) {
        const float cf = scoef[i];
        const f4 a = *reinterpret_cast<const f4*>(pb + (size_t)i * PSTRIDE + tid * 4);
        g[0] = fmaf(cf, a[0], g[0]);
        g[1] = fmaf(cf, a[1], g[1]);
        g[2] = fmaf(cf, a[2], g[2]);
        g[3] = fmaf(cf, a[3], g[3]);
    }
    g *= inv_l;

    const float s1 = g[0] + g[1] + g[2] + g[3];
    const float s2 = g[0]*g[0] + g[1]*g[1] + g[2]*g[2] + g[3]*g[3];
    sredA[tid] = s1; sredB[tid] = s2; __syncthreads();
    for (int off = 256; off > 0; off >>= 1) {
        if (tid < off) { sredA[tid] += sredA[tid + off]; sredB[tid] += sredB[tid + off]; }
        __syncthreads();
    }
    const float mean = sredA[0] / (float)D;
    const float var = sredB[0] / (float)D - mean * mean;
    const float rstd = rsqrtf(var + LN_EPS);

    const f4 ga = *reinterpret_cast<const f4*>(gamma + tid * 4);
    const f4 be = *reinterpret_cast<const f4*>(beta + tid * 4);
    f4 o;
    o[0] = (g[0] - mean) * rstd * ga[0] + be[0];
    o[1] = (g[1] - mean) * rstd * ga[1] + be[1];
    o[2] = (g[2] - mean) * rstd * ga[2] + be[2];
    o[3] = (g[3] - mean) * rstd * ga[3] + be[3];
    *reinterpret_cast<f4*>(out + (size_t)b * D + tid * 4) = o;
}

extern "C" void kernel_launch(void* const* d_in, const int* in_sizes, int n_in,
                              void* d_out, int out_size, void* d_ws, size_t ws_size,
                              hipStream_t stream) {
    const float* X     = (const float*)d_in[0];
    const float* query = (const float*)d_in[1];
    const float* Wq    = (const float*)d_in[2];
    const float* bq    = (const float*)d_in[3];
    const float* We    = (const float*)d_in[4];
    const float* be    = (const float*)d_in[5];
    const float* gamma = (const float*)d_in[6];
    const float* beta  = (const float*)d_in[7];
    float* out = (float*)d_out;
    float* ws  = (float*)d_ws;

    size_t avail = ws_size / 4;
    int cpb = 32;
    while (cpb > 1 && (size_t)PBASE + (size_t)NB * cpb * PSTRIDE > avail) cpb >>= 1;
    const int rpc = NS / cpb;

    hipLaunchKernelGGL(k_qq1, dim3(32), dim3(256), 0, stream, query, Wq, ws + PQ);
    hipLaunchKernelGGL(k_w, dim3(32), dim3(256), 0, stream, We, bq, be, ws);
    hipLaunchKernelGGL(k_main, dim3(cpb, NB), dim3(256), 0, stream,
                       X, ws, ws + PBASE, cpb, rpc);
    hipLaunchKernelGGL(k_fin, dim3(NB), dim3(512), 0, stream,
                       ws + PBASE, gamma, beta, out, cpb);
}